// Round 8
// baseline (150.889 us; speedup 1.0000x reference)
//
#include <hip/hip_runtime.h>

namespace {
constexpr int B = 2, C = 72, O = 72, H = 180, W = 320;
constexpr int K = 9, G = 9, Cg = 8, Og = 8;
constexpr int OFFC = 2 * K;           // 18 offset channels
constexpr int HW = H * W;             // 57600
constexpr size_t OFF_ELEMS = (size_t)B * OFFC * HW;   // 2,073,600 floats
constexpr int W1_ELEMS = OFFC * C * 9;                // 11664
constexpr int W2_ELEMS = O * Cg * 9;                  // 5184
constexpr int ICW = C / 4;            // 18 input channels per wave

// deform tile geometry: one block = one group x (64 wide x 4 tall) pixels
constexpr int TW = 64, TH = 4;
constexpr int HALO = 2;               // R7-validated; global fallback for tail
constexpr int NR = TH + 2 * HALO;     // 8 staged rows
constexpr int NC = TW + 2 * HALO;     // 68 staged cols
constexpr int TX = W / TW;            // 5
constexpr int TY = H / TH;            // 45
constexpr int NP = Cg / 2;            // 4 channel pairs

typedef float f2u __attribute__((ext_vector_type(2), aligned(4)));  // global
typedef float f2  __attribute__((ext_vector_type(2)));              // packed math
}

// ---------------------------------------------------------------------------
// Setup: transpose weights.
//   w1t[ic][tap][oc]        <- off_w[oc][ic][tap]
//   w2t[g][k][p][og][comp]  <- weight[g*8+og][2p+comp][k]   (pair-interleaved)
// ---------------------------------------------------------------------------
__global__ __launch_bounds__(256) void transpose_weights(
    const float* __restrict__ off_w,
    const float* __restrict__ weight,
    float* __restrict__ w1t,
    float* __restrict__ w2t)
{
    int i = blockIdx.x * blockDim.x + threadIdx.x;
    if (i < W1_ELEMS) {
        int oc = i % OFFC;
        int tap = (i / OFFC) % 9;
        int ic = i / (OFFC * 9);
        w1t[i] = off_w[(oc * C + ic) * 9 + tap];
    }
    if (i < W2_ELEMS) {
        int comp = i % 2;
        int og = (i / 2) % Og;
        int p  = (i / (2 * Og)) % NP;
        int k  = (i / (2 * Og * NP)) % K;
        int g  = i / (2 * Og * NP * K);
        int cg = 2 * p + comp;
        w2t[i] = weight[((g * Og + og) * Cg + cg) * 9 + k];
    }
}

// ---------------------------------------------------------------------------
// Kernel 1: 3x3 conv (C=72 -> 18) + bias. 4 waves split C; LDS reduce.
// (unchanged — ~30us; revisit only if it becomes dominant)
// ---------------------------------------------------------------------------
__global__ __launch_bounds__(256, 8) void offset_conv(
    const float* __restrict__ x,
    const float* __restrict__ w1t,
    const float* __restrict__ bias,
    float* __restrict__ offs)
{
    __shared__ float red[4 * 64 * OFFC];
    const int lane = threadIdx.x & 63;
    const int wave = threadIdx.x >> 6;

    const int g0 = blockIdx.x * 64;
    const int b = g0 / HW;
    const int pix = g0 - b * HW;
    const int yh = pix / W;
    const int x0b = pix - yh * W;
    const int xw = x0b + lane;

    float acc[OFFC];
    #pragma unroll
    for (int oc = 0; oc < OFFC; ++oc) acc[oc] = 0.f;

    const float* xb = x + (size_t)b * C * HW;
    const int ic0 = __builtin_amdgcn_readfirstlane(wave * ICW);

    const bool rv0 = (yh - 1) >= 0;
    const bool rv2 = (yh + 1) < H;

    #pragma unroll 3
    for (int ici = 0; ici < ICW; ++ici) {
        const int ic = ic0 + ici;
        const float* xc = xb + ic * HW;
        #pragma unroll
        for (int ky = 0; ky < 3; ++ky) {
            const int yy = yh + ky - 1;
            const bool rowv = (ky == 0) ? rv0 : (ky == 2 ? rv2 : true);
            if (!rowv) continue;
            const float* xr = xc + yy * W;
            #pragma unroll
            for (int kx = 0; kx < 3; ++kx) {
                const int xx = xw + kx - 1;
                const bool v = (xx >= 0) & (xx < W);
                const float val = v ? xr[xx] : 0.0f;
                const float* wp = w1t + (ic * 9 + ky * 3 + kx) * OFFC;
                #pragma unroll
                for (int oc = 0; oc < OFFC; ++oc)
                    acc[oc] = fmaf(val, wp[oc], acc[oc]);
            }
        }
    }

    #pragma unroll
    for (int oc = 0; oc < OFFC; ++oc)
        red[(wave * 64 + lane) * OFFC + oc] = acc[oc];
    __syncthreads();

    for (int e = threadIdx.x; e < 64 * OFFC; e += 256) {
        const int oc = e / 64;
        const int px = e - oc * 64;
        float s = bias[oc];
        #pragma unroll
        for (int w = 0; w < 4; ++w)
            s += red[(w * 64 + px) * OFFC + oc];
        offs[(size_t)b * OFFC * HW + (size_t)oc * HW + pix + px] = s;
    }
}

// ---------------------------------------------------------------------------
// Kernel 2: deformable grouped conv, LDS-staged (R7) + R8 changes:
//  - channel-PAIR interleaved LDS (f2 per (row,col)): one ds_read_b64 feeds
//    both channels -> DS ops halved, near-conflict-free b64 pattern
//  - packed fp32 math (<2 x float> -> v_pk_fma_f32): bilinear + og-matvec
//    accumulate two channels per instruction -> inner issue slots halved
//  - wave-uniform __all(interior) fast path skips clamp/select chain
// ---------------------------------------------------------------------------
__global__ __launch_bounds__(256) void deform_conv(
    const float* __restrict__ x,      // (B, C, H, W)
    const float* __restrict__ offs,   // (B, 18, H, W)
    const float* __restrict__ w2t,    // [g][k][p][og][2]
    float* __restrict__ out)          // (B, O, H, W)
{
    __shared__ f2 sm2[NP * NR * NC];       // 17,408 B

    const int bi = blockIdx.x;
    const int tx = bi % TX;
    const int ty = (bi / TX) % TY;
    const int g  = (bi / (TX * TY)) % G;
    const int b  = bi / (TX * TY * G);

    const int lane = threadIdx.x & 63;
    const int wrow = threadIdx.x >> 6;
    const int xw = tx * TW + lane;
    const int yh = ty * TH + wrow;

    const int gu = __builtin_amdgcn_readfirstlane(g);
    const float* wg = w2t + gu * (K * Cg * Og);
    const float* xg = x + ((size_t)b * C + gu * Cg) * HW;
    const float* offp = offs + (size_t)b * OFFC * HW + yh * W + xw;

    // Hoist offset loads (in flight while we stage).
    float dy[K], dx[K];
    #pragma unroll
    for (int k = 0; k < K; ++k) {
        dy[k] = offp[(size_t)(2 * k) * HW];
        dx[k] = offp[(size_t)(2 * k + 1) * HW];
    }

    // Stage window, channel-pair interleaved.
    const int wy = ty * TH - HALO;
    const int wx = tx * TW - HALO;
    for (int e = threadIdx.x; e < NP * NR * NC; e += 256) {
        const int c  = e % NC;
        const int rr = (e / NC) % NR;
        const int p  = e / (NC * NR);
        const int sy = min(max(wy + rr, 0), H - 1);
        const int sx = min(max(wx + c, 0), W - 1);
        const float* src = xg + (size_t)(2 * p) * HW + sy * W + sx;
        f2 v; v.x = src[0]; v.y = src[HW];
        sm2[e] = v;                        // ds_write_b64
    }
    __syncthreads();

    f2 accp[Og];
    #pragma unroll
    for (int og = 0; og < Og; ++og) accp[og] = (f2)0.f;

    #pragma unroll
    for (int k = 0; k < K; ++k) {
        float py = (float)(yh + k / 3 - 1) + dy[k];
        float px = (float)(xw + k % 3 - 1) + dx[k];
        float fy = floorf(py);
        float fx = floorf(px);
        int y0 = (int)fy, x0 = (int)fx;
        float wy1 = py - fy, wx1 = px - fx;
        float wy0 = 1.f - wy1, wx0 = 1.f - wx1;

        float w00, w01, w10, w11;
        int lr0, lr1, lcb, r0, r1;
        if (__all((y0 >= 0) & (y0 + 1 < H) & (x0 >= 0) & (x0 + 1 < W))) {
            // fully interior wave: no clamp/validity logic
            w00 = wy0 * wx0; w01 = wy0 * wx1;
            w10 = wy1 * wx0; w11 = wy1 * wx1;
            lr0 = y0 - wy; lr1 = lr0 + 1; lcb = x0 - wx;
            r0 = y0 * W + x0; r1 = r0 + W;
        } else {
            float hy0 = ((y0 >= 0) & (y0 < H)) ? wy0 : 0.f;
            float hy1 = ((y0 + 1 >= 0) & (y0 + 1 < H)) ? wy1 : 0.f;
            float gx0 = ((x0 >= 0) & (x0 < W)) ? wx0 : 0.f;
            float gx1 = ((x0 + 1 >= 0) & (x0 + 1 < W)) ? wx1 : 0.f;
            int y0c = min(max(y0, 0), H - 1);
            int y1c = min(max(y0 + 1, 0), H - 1);
            int x0c = min(max(x0, 0), W - 1);
            int x1c = min(max(x0 + 1, 0), W - 1);
            int xb2 = min(max(x0, 0), W - 2);
            float wA = (x0c == xb2 ? gx0 : 0.f) + (x1c == xb2 ? gx1 : 0.f);
            float wB = (x0c == xb2 + 1 ? gx0 : 0.f) + (x1c == xb2 + 1 ? gx1 : 0.f);
            w00 = hy0 * wA; w01 = hy0 * wB;
            w10 = hy1 * wA; w11 = hy1 * wB;
            lr0 = y0c - wy; lr1 = y1c - wy; lcb = xb2 - wx;
            r0 = y0c * W + xb2; r1 = y1c * W + xb2;
        }
        const bool inw = ((unsigned)lr0 < NR) & ((unsigned)lr1 < NR) &
                         ((unsigned)lcb < (NC - 1));
        const f2 w00_2 = w00, w01_2 = w01, w10_2 = w10, w11_2 = w11;
        const float* wkbase = wg + k * (Cg * Og);

        #pragma unroll
        for (int p = 0; p < NP; ++p) {
            f2 v2;
            if (inw) {
                const f2* s0 = sm2 + (p * NR + lr0) * NC + lcb;
                const f2* s1 = sm2 + (p * NR + lr1) * NC + lcb;
                f2 v = s0[0] * w00_2;                          // v_pk_mul_f32
                v = __builtin_elementwise_fma(s0[1], w01_2, v);
                v = __builtin_elementwise_fma(s1[0], w10_2, v);
                v = __builtin_elementwise_fma(s1[1], w11_2, v);
                v2 = v;
            } else {
                const float* xc0 = xg + (size_t)(2 * p) * HW;
                const float* xc1 = xc0 + HW;
                f2u a0 = *(const f2u*)(xc0 + r0);
                f2u b0 = *(const f2u*)(xc0 + r1);
                f2u a1 = *(const f2u*)(xc1 + r0);
                f2u b1 = *(const f2u*)(xc1 + r1);
                float v0 = w00 * a0.x;
                v0 = fmaf(w01, a0.y, v0);
                v0 = fmaf(w10, b0.x, v0);
                v0 = fmaf(w11, b0.y, v0);
                float v1 = w00 * a1.x;
                v1 = fmaf(w01, a1.y, v1);
                v1 = fmaf(w10, b1.x, v1);
                v1 = fmaf(w11, b1.y, v1);
                v2.x = v0; v2.y = v1;
            }
            const f2* wkp2 = (const f2*)(wkbase + p * (2 * Og));
            #pragma unroll
            for (int og = 0; og < Og; ++og)
                accp[og] = __builtin_elementwise_fma(v2, wkp2[og], accp[og]);
        }
    }

    float* op = out + ((size_t)b * O + gu * Og) * HW + yh * W + xw;
    #pragma unroll
    for (int og = 0; og < Og; ++og)
        op[(size_t)og * HW] = accp[og].x + accp[og].y;
}

extern "C" void kernel_launch(void* const* d_in, const int* in_sizes, int n_in,
                              void* d_out, int out_size, void* d_ws, size_t ws_size,
                              hipStream_t stream) {
    const float* input       = (const float*)d_in[0];
    const float* offset_feat = (const float*)d_in[1];
    const float* weight      = (const float*)d_in[2];
    const float* off_w       = (const float*)d_in[3];
    const float* off_b       = (const float*)d_in[4];
    float* out = (float*)d_out;

    float* offs = (float*)d_ws;
    float* w1t = offs + OFF_ELEMS;
    float* w2t = w1t + W1_ELEMS;

    transpose_weights<<<(W1_ELEMS + 255) / 256, 256, 0, stream>>>(off_w, weight, w1t, w2t);
    offset_conv<<<(B * HW) / 64, 256, 0, stream>>>(offset_feat, w1t, off_b, offs);
    deform_conv<<<B * G * TX * TY, 256, 0, stream>>>(input, offs, w2t, out);
}

// Round 9
// 97.055 us; speedup vs baseline: 1.5547x; 1.5547x over previous
//
#include <hip/hip_runtime.h>

namespace {
constexpr int B = 2, C = 72, O = 72, H = 180, W = 320;
constexpr int K = 9, G = 9, Cg = 8, Og = 8;
constexpr int OFFC = 2 * K;           // 18 offset channels
constexpr int HW = H * W;             // 57600
constexpr size_t OFF_ELEMS = (size_t)B * OFFC * HW;   // 2,073,600 floats
constexpr int W1_ELEMS = OFFC * C * 9;                // 11664
constexpr int W2_ELEMS = O * Cg * 9;                  // 5184
constexpr int ICW = C / 4;            // 18 input channels per wave

// deform tile geometry: one block = one group x (64 wide x 4 tall) pixels
constexpr int TW = 64, TH = 4;
constexpr int HALO = 2;               // R7-validated; global fallback for tail
constexpr int NR = TH + 2 * HALO;     // 8 staged rows
constexpr int NC = TW + 2 * HALO;     // 68 staged cols
constexpr int TX = W / TW;            // 5
constexpr int TY = H / TH;            // 45

typedef float f2u __attribute__((ext_vector_type(2), aligned(4)));
}

// ---------------------------------------------------------------------------
// Setup: transpose weights for contiguous wave-uniform (scalar) access.
//   w1t[ic][tap][oc]   <- off_w[oc][ic][tap]
//   w2t[g][k][cg][og]  <- weight[g*8+og][cg][k]
// ---------------------------------------------------------------------------
__global__ __launch_bounds__(256) void transpose_weights(
    const float* __restrict__ off_w,
    const float* __restrict__ weight,
    float* __restrict__ w1t,
    float* __restrict__ w2t)
{
    int i = blockIdx.x * blockDim.x + threadIdx.x;
    if (i < W1_ELEMS) {
        int oc = i % OFFC;
        int tap = (i / OFFC) % 9;
        int ic = i / (OFFC * 9);
        w1t[i] = off_w[(oc * C + ic) * 9 + tap];
    }
    if (i < W2_ELEMS) {
        int og = i % Og;
        int cg = (i / Og) % Cg;
        int k = (i / (Og * Cg)) % K;
        int g = i / (Og * Cg * K);
        w2t[i] = weight[((g * Og + og) * Cg + cg) * 9 + k];
    }
}

// ---------------------------------------------------------------------------
// Kernel 1: 3x3 conv (C=72 -> 18) + bias. 4 waves split C; LDS reduce.
// ic0 via readfirstlane -> provably wave-uniform weight addrs -> s_load.
// ---------------------------------------------------------------------------
__global__ __launch_bounds__(256, 8) void offset_conv(
    const float* __restrict__ x,
    const float* __restrict__ w1t,
    const float* __restrict__ bias,
    float* __restrict__ offs)
{
    __shared__ float red[4 * 64 * OFFC];
    const int lane = threadIdx.x & 63;
    const int wave = threadIdx.x >> 6;

    const int g0 = blockIdx.x * 64;
    const int b = g0 / HW;
    const int pix = g0 - b * HW;
    const int yh = pix / W;
    const int x0b = pix - yh * W;
    const int xw = x0b + lane;

    float acc[OFFC];
    #pragma unroll
    for (int oc = 0; oc < OFFC; ++oc) acc[oc] = 0.f;

    const float* xb = x + (size_t)b * C * HW;
    const int ic0 = __builtin_amdgcn_readfirstlane(wave * ICW);

    const bool rv0 = (yh - 1) >= 0;
    const bool rv2 = (yh + 1) < H;

    #pragma unroll 3
    for (int ici = 0; ici < ICW; ++ici) {
        const int ic = ic0 + ici;
        const float* xc = xb + ic * HW;
        #pragma unroll
        for (int ky = 0; ky < 3; ++ky) {
            const int yy = yh + ky - 1;
            const bool rowv = (ky == 0) ? rv0 : (ky == 2 ? rv2 : true);
            if (!rowv) continue;
            const float* xr = xc + yy * W;
            #pragma unroll
            for (int kx = 0; kx < 3; ++kx) {
                const int xx = xw + kx - 1;
                const bool v = (xx >= 0) & (xx < W);
                const float val = v ? xr[xx] : 0.0f;
                const float* wp = w1t + (ic * 9 + ky * 3 + kx) * OFFC;
                #pragma unroll
                for (int oc = 0; oc < OFFC; ++oc)
                    acc[oc] = fmaf(val, wp[oc], acc[oc]);
            }
        }
    }

    #pragma unroll
    for (int oc = 0; oc < OFFC; ++oc)
        red[(wave * 64 + lane) * OFFC + oc] = acc[oc];
    __syncthreads();

    for (int e = threadIdx.x; e < 64 * OFFC; e += 256) {
        const int oc = e / 64;
        const int px = e - oc * 64;
        float s = bias[oc];
        #pragma unroll
        for (int w = 0; w < 4; ++w)
            s += red[(w * 64 + px) * OFFC + oc];
        offs[(size_t)b * OFFC * HW + (size_t)oc * HW + pix + px] = s;
    }
}

// ---------------------------------------------------------------------------
// Kernel 2: deformable grouped conv, LDS-staged. R9 = R7 (68us, 36 VGPR,
// scalar math — R8's packed fp32 reverted) + two VALU-count cuts:
//  (1) staging addressing without div/mod: Cg*NR = 64 rows exactly; wave
//      handles rows (4i+wave) -> ch=row>>3, rr=row&7 free; row base scalar;
//      one tail pass covers cols 64..67 (thread t -> row t>>2, col 64+(t&3)).
//  (2) wave-uniform __all(interior) fast path skips clamp/select per tap
//      (~94% of wave-taps), scalar math so no register inflation.
// Bank-conflict note: SQ_LDS_BANK_CONFLICT ~9.7M constant across R6/R7/R8
// (~2 cyc/DS instr) = structural 64-lane/32-bank aliasing -> not chased.
// ---------------------------------------------------------------------------
__global__ __launch_bounds__(256) void deform_conv(
    const float* __restrict__ x,      // (B, C, H, W)
    const float* __restrict__ offs,   // (B, 18, H, W)
    const float* __restrict__ w2t,    // [g][k][cg][og]
    float* __restrict__ out)          // (B, O, H, W)
{
    __shared__ float sm[Cg * NR * NC];     // 17,408 B

    const int bi = blockIdx.x;
    const int tx = bi % TX;
    const int ty = (bi / TX) % TY;
    const int g  = (bi / (TX * TY)) % G;
    const int b  = bi / (TX * TY * G);

    const int lane = threadIdx.x & 63;
    const int wave = threadIdx.x >> 6;
    const int xw = tx * TW + lane;
    const int yh = ty * TH + wave;

    const int gu = __builtin_amdgcn_readfirstlane(g);
    const float* wg = w2t + gu * (K * Cg * Og);
    const float* xg = x + ((size_t)b * C + gu * Cg) * HW;
    const float* offp = offs + (size_t)b * OFFC * HW + yh * W + xw;

    // Hoist offset loads (in flight while we stage).
    float dy[K], dx[K];
    #pragma unroll
    for (int k = 0; k < K; ++k) {
        dy[k] = offp[(size_t)(2 * k) * HW];
        dx[k] = offp[(size_t)(2 * k + 1) * HW];
    }

    // Stage window [wy, wy+NR) x [wx, wx+NC) for 8 channels.
    const int wy = ty * TH - HALO;
    const int wx = tx * TW - HALO;
    {
        const int sxl = min(max(wx + lane, 0), W - 1);   // per-lane, once
        #pragma unroll
        for (int i = 0; i < 16; ++i) {
            const int rowi = 4 * i + wave;               // 0..63, wave-uniform
            const int ch = rowi >> 3;
            const int rr = rowi & 7;
            const int sy = min(max(wy + rr, 0), H - 1);  // wave-uniform (SALU)
            sm[rowi * NC + lane] = xg[ch * HW + sy * W + sxl];
        }
        // tail cols 64..67: thread t -> row t>>2, col 64+(t&3)
        const int rowt = threadIdx.x >> 2;
        const int ct = 64 + (threadIdx.x & 3);
        const int cht = rowt >> 3;
        const int rrt = rowt & 7;
        const int syt = min(max(wy + rrt, 0), H - 1);
        const int sxt = min(max(wx + ct, 0), W - 1);
        sm[rowt * NC + ct] = xg[cht * HW + syt * W + sxt];
    }
    __syncthreads();

    float acc[Og];
    #pragma unroll
    for (int og = 0; og < Og; ++og) acc[og] = 0.f;

    #pragma unroll
    for (int k = 0; k < K; ++k) {
        float py = (float)(yh + k / 3 - 1) + dy[k];
        float px = (float)(xw + k % 3 - 1) + dx[k];
        float fy = floorf(py);
        float fx = floorf(px);
        int y0 = (int)fy, x0 = (int)fx;
        float wy1 = py - fy, wx1 = px - fx;
        float wy0 = 1.f - wy1, wx0 = 1.f - wx1;

        float w00, w01, w10, w11;
        int lr0, lr1, lcb, r0, r1;
        if (__all((y0 >= 0) & (y0 + 1 < H) & (x0 >= 0) & (x0 + 1 < W))) {
            // fully interior wave: no clamp/validity logic needed
            w00 = wy0 * wx0; w01 = wy0 * wx1;
            w10 = wy1 * wx0; w11 = wy1 * wx1;
            lr0 = y0 - wy; lr1 = lr0 + 1; lcb = x0 - wx;
            r0 = y0 * W + x0; r1 = r0 + W;
        } else {
            float hy0 = ((y0 >= 0) & (y0 < H)) ? wy0 : 0.f;
            float hy1 = ((y0 + 1 >= 0) & (y0 + 1 < H)) ? wy1 : 0.f;
            float gx0 = ((x0 >= 0) & (x0 < W)) ? wx0 : 0.f;
            float gx1 = ((x0 + 1 >= 0) & (x0 + 1 < W)) ? wx1 : 0.f;
            int y0c = min(max(y0, 0), H - 1);
            int y1c = min(max(y0 + 1, 0), H - 1);
            int x0c = min(max(x0, 0), W - 1);
            int x1c = min(max(x0 + 1, 0), W - 1);
            int xb2 = min(max(x0, 0), W - 2);
            float wA = (x0c == xb2 ? gx0 : 0.f) + (x1c == xb2 ? gx1 : 0.f);
            float wB = (x0c == xb2 + 1 ? gx0 : 0.f) + (x1c == xb2 + 1 ? gx1 : 0.f);
            w00 = hy0 * wA; w01 = hy0 * wB;
            w10 = hy1 * wA; w11 = hy1 * wB;
            lr0 = y0c - wy; lr1 = y1c - wy; lcb = xb2 - wx;
            r0 = y0c * W + xb2; r1 = y1c * W + xb2;
        }
        const bool inw = ((unsigned)lr0 < NR) & ((unsigned)lr1 < NR) &
                         ((unsigned)lcb < (NC - 1));
        const float* wk = wg + k * (Cg * Og);

        if (inw) {
            const float* s0 = sm + lr0 * NC + lcb;
            const float* s1 = sm + lr1 * NC + lcb;
            #pragma unroll
            for (int cg = 0; cg < Cg; ++cg) {
                const int o = cg * (NR * NC);
                float v = w00 * s0[o];
                v = fmaf(w01, s0[o + 1], v);
                v = fmaf(w10, s1[o], v);
                v = fmaf(w11, s1[o + 1], v);
                #pragma unroll
                for (int og = 0; og < Og; ++og)
                    acc[og] = fmaf(v, wk[cg * Og + og], acc[og]);
            }
        } else {
            #pragma unroll
            for (int cg = 0; cg < Cg; ++cg) {
                const float* xc = xg + cg * HW;
                f2u a0 = *(const f2u*)(xc + r0);
                f2u a1 = *(const f2u*)(xc + r1);
                float v = w00 * a0.x;
                v = fmaf(w01, a0.y, v);
                v = fmaf(w10, a1.x, v);
                v = fmaf(w11, a1.y, v);
                #pragma unroll
                for (int og = 0; og < Og; ++og)
                    acc[og] = fmaf(v, wk[cg * Og + og], acc[og]);
            }
        }
    }
    float* op = out + ((size_t)b * O + gu * Og) * HW + yh * W + xw;
    #pragma unroll
    for (int og = 0; og < Og; ++og) op[(size_t)og * HW] = acc[og];
}

extern "C" void kernel_launch(void* const* d_in, const int* in_sizes, int n_in,
                              void* d_out, int out_size, void* d_ws, size_t ws_size,
                              hipStream_t stream) {
    const float* input       = (const float*)d_in[0];
    const float* offset_feat = (const float*)d_in[1];
    const float* weight      = (const float*)d_in[2];
    const float* off_w       = (const float*)d_in[3];
    const float* off_b       = (const float*)d_in[4];
    float* out = (float*)d_out;

    float* offs = (float*)d_ws;
    float* w1t = offs + OFF_ELEMS;
    float* w2t = w1t + W1_ELEMS;

    transpose_weights<<<(W1_ELEMS + 255) / 256, 256, 0, stream>>>(off_w, weight, w1t, w2t);
    offset_conv<<<(B * HW) / 64, 256, 0, stream>>>(offset_feat, w1t, off_b, offs);
    deform_conv<<<B * G * TX * TY, 256, 0, stream>>>(input, offs, w2t, out);
}